// Round 12
// baseline (479.974 us; speedup 1.0000x reference)
//
#include <hip/hip_runtime.h>

#define S_LEN 2048
#define D_DIM 128
#define BN 64

typedef __attribute__((ext_vector_type(8))) short short8;
typedef __attribute__((ext_vector_type(4))) float floatx4;
typedef __attribute__((ext_vector_type(4))) unsigned uintx4;
typedef unsigned short u16;

__device__ __forceinline__ u16 f2b(float f) {
    union { float f; unsigned u; } x; x.f = f;
    unsigned r = x.u + 0x7FFFu + ((x.u >> 16) & 1u);  // RNE
    return (u16)(r >> 16);
}
__device__ __forceinline__ float b2f(u16 h) {
    union { unsigned u; float f; } x; x.u = ((unsigned)h) << 16;
    return x.f;
}
__device__ __forceinline__ void gld_lds16(const void* g, void* l) {
    __builtin_amdgcn_global_load_lds(
        (const __attribute__((address_space(1))) unsigned int*)g,
        (__attribute__((address_space(3))) unsigned int*)l, 16, 0, 0);
}
__device__ __forceinline__ floatx4 mfma16(short8 a, short8 b, floatx4 c) {
    return __builtin_amdgcn_mfma_f32_16x16x32_bf16(a, b, c, 0, 0, 0);
}

// ---------------- fused pre-pass: K fp32->bf16 (x<32) | V transpose (x>=32) ----
// UNCHANGED from r15/r16 (run-verified R10/R11, absmax 0.0156).
__global__ __launch_bounds__(256) void prep_kv(const float* __restrict__ k,
                                               const float* __restrict__ v,
                                               u16* __restrict__ kw,
                                               u16* __restrict__ vt) {
    const int x   = blockIdx.x;
    const int bh  = blockIdx.y;
    const int tid = threadIdx.x;
    if (x < 32) {
        const float* src = k + (size_t)bh * S_LEN * D_DIM + (size_t)x * 8192;
        u16* dst = kw + (size_t)bh * S_LEN * D_DIM + (size_t)x * 8192;
        #pragma unroll
        for (int i = 0; i < 8; ++i) {
            int e = i * 1024 + tid * 4;
            float4 xx = *(const float4*)(src + e);
            ushort4 h;
            h.x = f2b(xx.x); h.y = f2b(xx.y); h.z = f2b(xx.z); h.w = f2b(xx.w);
            *(ushort4*)(dst + e) = h;
        }
    } else {
        __shared__ float T[128][65];
        const int t  = x - 32;            // 0..31
        const int s0 = (t >> 1) * 128;
        const int d0 = (t & 1) * 64;
        const float* vb = v + ((size_t)bh * S_LEN + s0) * D_DIM + d0;
        #pragma unroll
        for (int i = 0; i < 8; ++i) {
            int unit = i * 256 + tid;
            int ss = unit >> 4;
            int c  = (unit & 15) * 4;
            float4 xx = *(const float4*)(vb + ss * D_DIM + c);
            T[ss][c + 0] = xx.x; T[ss][c + 1] = xx.y;
            T[ss][c + 2] = xx.z; T[ss][c + 3] = xx.w;
        }
        __syncthreads();
        u16* ob = vt + (size_t)bh * D_DIM * S_LEN + (size_t)d0 * S_LEN + s0;
        #pragma unroll
        for (int i = 0; i < 8; ++i) {
            int unit = i * 256 + tid;
            int d  = unit >> 5;
            int sl = (unit & 31) * 4;
            ushort4 h;
            h.x = f2b(T[sl + 0][d]); h.y = f2b(T[sl + 1][d]);
            h.z = f2b(T[sl + 2][d]); h.w = f2b(T[sl + 3][d]);
            *(ushort4*)(ob + (size_t)d * S_LEN + sl) = h;
        }
    }
}

// r17: BM=256 via 16-WAVE (1024-thread) m=1 blocks + C9 9-tile walker.
// R10 vs R11: per-CU visit-pair time (~5.2us) is INVARIANT to per-wave work
// (halved LDS reads, same time) and to waves/CU -> per-visit cost is block
// CADENCE (barrier + stage drain + serial softmax), not per-wave volume.
// Only lever: fewer visits. BM=256 -> 4608 total visits (was 8704), 512
// blocks x 9 tiles, 2 blocks/CU (2048 thr = FULL occupancy), per-CU 9
// visit-pairs. Cadence model predicts fa ~ 9x5.2 ~ 47us; null ~ 88.
// Per-wave body byte-identical to R10's proven 64-VGPR m=1 kernel.
// C9 tables run-verified in R8; ws 98.6MB = exactly R8's proven bound.
__constant__ signed char C9_QT[23] = {0,1, 1,2, 2,3, 3, 3,4, 4, 4,5, 5, 5, 5,6, 6, 6, 6,7, 7, 7, 7};
__constant__ signed char C9_T0[23] = {0,0, 5,0, 6,0, 3,12,0, 5,14,0, 3,12,21,0, 6,15,24,0, 5,14,23};
__constant__ signed char C9_T1[23] = {4,5, 8,6,12,3,12,16,5,14,20,3,12,21,24,6,15,24,28,5,14,23,32};
__constant__ signed char C9_P [23] = {-1,0, 1,0, 1,0, 1, 2,0, 1, 2,0, 1, 2, 3,0, 1, 2, 3,0, 1, 2, 3};
__constant__ signed char C9_OFF[17] = {0,2,4,6,7,9,10,12,13,14,16,17,18,20,21,22,23};
__constant__ signed char C9_NP[8] = {1,2,2,3,3,4,4,4};
__constant__ signed char C9_EB[8] = {0,0,1,2,4,6,9,12};

__global__ __launch_bounds__(1024, 8) void fa_bal(const float* __restrict__ q,
                                                  const u16* __restrict__ kw,
                                                  const u16* __restrict__ vtw,
                                                  float* __restrict__ out,
                                                  float* __restrict__ phi,
                                                  float* __restrict__ mlb) {
    __shared__ u16 Ks[2][BN * D_DIM];
    __shared__ u16 Vt[2][D_DIM * BN];

    const int bh = blockIdx.x & 31;
    const int s  = blockIdx.x >> 5;        // 16 slots/bh, all exactly 9 tiles
    const int tid  = threadIdx.x;
    const int w    = tid >> 6;             // 0..15
    const int lane = tid & 63;
    const int ln   = lane & 15;
    const int quad = lane >> 4;
    constexpr float qs = 0.08838834764831845f * 1.44269504088896340f;

    const u16* kb_bh = kw + (size_t)bh * S_LEN * D_DIM;
    const u16* vb_bh = vtw + (size_t)bh * D_DIM * S_LEN;

    auto stage = [&](int t, int b) {
        const int n0 = t * BN;
        const u16* kb = kb_bh + (size_t)n0 * D_DIM;
        {
            int R0 = w * 4;                // 16 waves x 4 rows = 64
            int r = R0 + (lane >> 4);
            int p = lane & 15;
            gld_lds16(kb + r * D_DIM + ((p ^ (r & 7)) << 3), &Ks[b][R0 * D_DIM]);
        }
        {
            int D0 = w * 8;                // 16 waves x 8 rows = 128
            int d = D0 + (lane >> 3);
            int p = lane & 7;
            gld_lds16(vb_bh + (size_t)d * S_LEN + n0 + ((p ^ (d & 7)) << 3),
                      &Vt[b][D0 * BN]);
        }
    };

    const int cbeg = C9_OFF[s], cend = C9_OFF[s + 1];
    int pb = 0;
    stage(C9_T0[cbeg], 0);

    for (int c = cbeg; c < cend; ++c) {
        const int qt = C9_QT[c], t0 = C9_T0[c], t1 = C9_T1[c];
        const int pp = C9_P[c];
        const int q0 = qt * 256;
        const int rowb0 = q0 + w * 16;     // this wave's 16 q-rows: rowb0 + ln

        // ---- Q fragments (scale*log2e folded) ----
        short8 qf[4];
        {
            const float* qrow = q + ((size_t)bh * S_LEN + rowb0 + ln) * D_DIM;
            #pragma unroll
            for (int kc = 0; kc < 4; ++kc) {
                const float* p = qrow + kc * 32 + quad * 8;
                float4 x0 = *(const float4*)(p);
                float4 x1 = *(const float4*)(p + 4);
                short8 f;
                f[0] = (short)f2b(x0.x * qs); f[1] = (short)f2b(x0.y * qs);
                f[2] = (short)f2b(x0.z * qs); f[3] = (short)f2b(x0.w * qs);
                f[4] = (short)f2b(x1.x * qs); f[5] = (short)f2b(x1.y * qs);
                f[6] = (short)f2b(x1.z * qs); f[7] = (short)f2b(x1.w * qs);
                qf[kc] = f;
            }
        }

        floatx4 o[8];
        #pragma unroll
        for (int db = 0; db < 8; ++db) o[db] = (floatx4){0.f, 0.f, 0.f, 0.f};
        float m_i = -1e30f;
        float l_i = 0.f;

        for (int t = t0; t < t1; ++t) {
            __syncthreads();
            {
                int nt = (t + 1 < t1) ? (t + 1) : ((c + 1 < cend) ? (int)C9_T0[c + 1] : -1);
                if (nt >= 0) stage(nt, pb ^ 1);
            }
            const u16* ks = Ks[pb];
            const u16* vs = Vt[pb];
            pb ^= 1;
            const int n0 = t * BN;
            if (n0 > rowb0 + 15) continue;   // wave-uniform: fully masked tile

            // ---- S^T = K Q^T ----
            floatx4 sc[4];
            #pragma unroll
            for (int nb = 0; nb < 4; ++nb) {
                short8 kf[4];
                #pragma unroll
                for (int kc = 0; kc < 4; ++kc) {
                    int r = nb * 16 + ln;
                    kf[kc] = *(const short8*)&ks[r * D_DIM + (((kc * 4 + quad) ^ (r & 7)) << 3)];
                }
                floatx4 a = (floatx4){0.f, 0.f, 0.f, 0.f};
                #pragma unroll
                for (int kc = 0; kc < 4; ++kc) a = mfma16(kf[kc], qf[kc], a);
                sc[nb] = a;
            }

            // ---- mask, online softmax (T13), B-frag build ----
            const int qrow = rowb0 + ln;
            if (n0 + 63 > rowb0) {
                #pragma unroll
                for (int nb = 0; nb < 4; ++nb) {
                    int kvb = n0 + nb * 16 + quad * 4;
                    #pragma unroll
                    for (int r = 0; r < 4; ++r)
                        if (kvb + r > qrow) sc[nb][r] = -1e30f;
                }
            }
            float mx;
            {
                floatx4 m01, m23;
                #pragma unroll
                for (int r = 0; r < 4; ++r) {
                    m01[r] = fmaxf(sc[0][r], sc[1][r]);
                    m23[r] = fmaxf(sc[2][r], sc[3][r]);
                }
                floatx4 mm;
                #pragma unroll
                for (int r = 0; r < 4; ++r) mm[r] = fmaxf(m01[r], m23[r]);
                mx = fmaxf(fmaxf(mm[0], mm[1]), fmaxf(mm[2], mm[3]));
            }
            mx = fmaxf(mx, __shfl_xor(mx, 16));
            mx = fmaxf(mx, __shfl_xor(mx, 32));
            if (!__all(mx <= m_i + 8.f)) {
                float mn = fmaxf(m_i, mx);
                float al = __builtin_amdgcn_exp2f(m_i - mn);
                m_i = mn;
                l_i *= al;
                #pragma unroll
                for (int db = 0; db < 8; ++db) o[db] *= al;
            }
            const float mn = m_i;
            float rsn[4];
            unsigned pk0[4], pk1[4];
            #pragma unroll
            for (int nb = 0; nb < 4; ++nb) {
                u16 h[4];
                #pragma unroll
                for (int r = 0; r < 4; ++r) {
                    float p = __builtin_amdgcn_exp2f(sc[nb][r] - mn);
                    h[r] = f2b(p);
                }
                rsn[nb] = (b2f(h[0]) + b2f(h[1])) + (b2f(h[2]) + b2f(h[3]));
                pk0[nb] = (unsigned)h[0] | ((unsigned)h[1] << 16);
                pk1[nb] = (unsigned)h[2] | ((unsigned)h[3] << 16);
            }
            float rs = (rsn[0] + rsn[1]) + (rsn[2] + rsn[3]);
            rs += __shfl_xor(rs, 16);
            rs += __shfl_xor(rs, 32);
            l_i += rs;

            short8 bfr[2];
            const int s0l = ((quad & 1) << 5) + ln;
            const int s1l = s0l + 16;
            const bool hiq = (quad >> 1) != 0;
            #pragma unroll
            for (int p = 0; p < 2; ++p) {
                unsigned l0 = __shfl((int)pk0[2 * p], s0l), h0 = __shfl((int)pk0[2 * p + 1], s0l);
                unsigned l1 = __shfl((int)pk1[2 * p], s0l), h1 = __shfl((int)pk1[2 * p + 1], s0l);
                unsigned l2 = __shfl((int)pk0[2 * p], s1l), h2 = __shfl((int)pk0[2 * p + 1], s1l);
                unsigned l3 = __shfl((int)pk1[2 * p], s1l), h3 = __shfl((int)pk1[2 * p + 1], s1l);
                union { uintx4 u; short8 s; } bc;
                bc.u = (uintx4){hiq ? h0 : l0, hiq ? h1 : l1, hiq ? h2 : l2, hiq ? h3 : l3};
                bfr[p] = bc.s;
            }

            // ---- O^T += V^T P^T ----
            #pragma unroll
            for (int db = 0; db < 8; ++db) {
                int d = db * 16 + ln;
                short8 v0 = *(const short8*)&vs[d * BN + ((quad ^ (d & 7)) << 3)];
                short8 v1 = *(const short8*)&vs[d * BN + (((4 + quad) ^ (d & 7)) << 3)];
                o[db] = mfma16(v0, bfr[0], o[db]);
                o[db] = mfma16(v1, bfr[1], o[db]);
            }
        }

        // ---- chunk epilogue ----
        if (pp < 0) {
            float inv = 1.f / l_i;
            size_t row = (size_t)bh * S_LEN + rowb0 + ln;
            float* orow = out + row * D_DIM + quad * 4;
            #pragma unroll
            for (int db = 0; db < 8; ++db) {
                float4 st = {o[db][0] * inv, o[db][1] * inv,
                             o[db][2] * inv, o[db][3] * inv};
                *(float4*)(orow + db * 16) = st;
            }
        } else {
            const int r = w * 16 + ln;                 // row within q-tile 0..255
            float* base = (pp == 0)
                ? out + ((size_t)bh * S_LEN + q0) * D_DIM
                : phi + (size_t)(bh * 15 + C9_EB[qt] + pp - 1) * (256 * D_DIM);
            float* orow = base + (size_t)r * D_DIM + quad * 4;
            #pragma unroll
            for (int db = 0; db < 8; ++db) {
                float4 st = {o[db][0], o[db][1], o[db][2], o[db][3]};
                *(float4*)(orow + db * 16) = st;
            }
            if (quad == 0) {
                float* mlq = mlb + (size_t)((bh * 8 + qt) * 4 + pp) * 512;
                mlq[r] = m_i;
                mlq[256 + r] = l_i;
            }
        }
    }
}

// ---------------- np-way flash-combine (log2 domain), r13 version ------------
__global__ __launch_bounds__(512) void merge9(float* __restrict__ out,
                                              const float* __restrict__ phi,
                                              const float* __restrict__ mlb) {
    const int item = blockIdx.x;         // 7*32: qt 1..7 x bh
    const int qt = 1 + (item % 7);
    const int bh = item / 7;
    const int np = C9_NP[qt];
    const int eb = C9_EB[qt];
    const int tid = threadIdx.x;
    const int r  = tid >> 1;             // row 0..255
    const int hf = (tid & 1) * 64;       // d half
    const size_t mlB = (size_t)((bh * 8 + qt) * 4) * 512;
    float mP[4], lP[4];
    mP[0] = mlb[mlB + r]; lP[0] = mlb[mlB + 256 + r];
    float ms = mP[0];
    #pragma unroll
    for (int p = 1; p < 4; ++p) {
        if (p < np) {
            mP[p] = mlb[mlB + p * 512 + r];
            lP[p] = mlb[mlB + p * 512 + 256 + r];
            ms = fmaxf(ms, mP[p]);
        }
    }
    float a[4], ls = 0.f;
    #pragma unroll
    for (int p = 0; p < 4; ++p) {
        if (p < np) {
            a[p] = __builtin_amdgcn_exp2f(mP[p] - ms);
            ls += lP[p] * a[p];
        }
    }
    float inv = 1.f / ls;
    float* orow = out + ((size_t)bh * S_LEN + qt * 256 + r) * D_DIM + hf;
    const float* e1 = phi + ((size_t)(bh * 15 + eb + 0) * 256 + r) * D_DIM + hf;
    const float* e2 = phi + ((size_t)(bh * 15 + eb + 1) * 256 + r) * D_DIM + hf;
    const float* e3 = phi + ((size_t)(bh * 15 + eb + 2) * 256 + r) * D_DIM + hf;
    #pragma unroll
    for (int i = 0; i < 16; ++i) {
        float4 acc = *(const float4*)(orow + i * 4);
        acc.x *= a[0]; acc.y *= a[0]; acc.z *= a[0]; acc.w *= a[0];
        if (np > 1) {
            float4 e = *(const float4*)(e1 + i * 4);
            acc.x += e.x * a[1]; acc.y += e.y * a[1]; acc.z += e.z * a[1]; acc.w += e.w * a[1];
        }
        if (np > 2) {
            float4 e = *(const float4*)(e2 + i * 4);
            acc.x += e.x * a[2]; acc.y += e.y * a[2]; acc.z += e.z * a[2]; acc.w += e.w * a[2];
        }
        if (np > 3) {
            float4 e = *(const float4*)(e3 + i * 4);
            acc.x += e.x * a[3]; acc.y += e.y * a[3]; acc.z += e.z * a[3]; acc.w += e.w * a[3];
        }
        float4 st = {acc.x * inv, acc.y * inv, acc.z * inv, acc.w * inv};
        *(float4*)(orow + i * 4) = st;
    }
}

extern "C" void kernel_launch(void* const* d_in, const int* in_sizes, int n_in,
                              void* d_out, int out_size, void* d_ws, size_t ws_size,
                              hipStream_t stream) {
    const float* q = (const float*)d_in[0];
    const float* k = (const float*)d_in[1];
    const float* v = (const float*)d_in[2];
    float* out = (float*)d_out;
    const int nbh = in_sizes[0] / (S_LEN * D_DIM);    // 32
    const size_t kelems = (size_t)nbh * S_LEN * D_DIM;

    u16* kw = (u16*)d_ws;                               // 16.78 MB
    u16* vt = kw + kelems;                              // 16.78 MB
    float* phi = (float*)(vt + kelems);                 // 15*nbh*256*128 f32 = 62.9 MB
    float* mlb = phi + (size_t)15 * nbh * 256 * D_DIM;  // nbh*8*4*512 f32 = 2.1 MB
    // total 98.6 MB == exactly the bound R8 proved available.

    prep_kv<<<dim3(64, nbh), 256, 0, stream>>>(k, v, kw, vt);
    fa_bal<<<dim3(16 * nbh), 1024, 0, stream>>>(q, kw, vt, out, phi, mlb);
    merge9<<<dim3(7 * nbh), 512, 0, stream>>>(out, phi, mlb);
}

// Round 13
// 248.543 us; speedup vs baseline: 1.9311x; 1.9311x over previous
//
#include <hip/hip_runtime.h>

#define S_LEN 2048
#define D_DIM 128
#define BN 64

typedef __attribute__((ext_vector_type(8))) short short8;
typedef __attribute__((ext_vector_type(4))) float floatx4;
typedef __attribute__((ext_vector_type(4))) unsigned uintx4;
typedef unsigned short u16;

__device__ __forceinline__ u16 f2b(float f) {
    union { float f; unsigned u; } x; x.f = f;
    unsigned r = x.u + 0x7FFFu + ((x.u >> 16) & 1u);  // RNE
    return (u16)(r >> 16);
}
__device__ __forceinline__ float b2f(u16 h) {
    union { unsigned u; float f; } x; x.u = ((unsigned)h) << 16;
    return x.f;
}
__device__ __forceinline__ void gld_lds16(const void* g, void* l) {
    __builtin_amdgcn_global_load_lds(
        (const __attribute__((address_space(1))) unsigned int*)g,
        (__attribute__((address_space(3))) unsigned int*)l, 16, 0, 0);
}
__device__ __forceinline__ floatx4 mfma16(short8 a, short8 b, floatx4 c) {
    return __builtin_amdgcn_mfma_f32_16x16x32_bf16(a, b, c, 0, 0, 0);
}

// ---------------- fused pre-pass: K fp32->bf16 (x<32) | V transpose (x>=32) ----
// UNCHANGED (run-verified R10/R11, absmax 0.0156).
__global__ __launch_bounds__(256) void prep_kv(const float* __restrict__ k,
                                               const float* __restrict__ v,
                                               u16* __restrict__ kw,
                                               u16* __restrict__ vt) {
    const int x   = blockIdx.x;
    const int bh  = blockIdx.y;
    const int tid = threadIdx.x;
    if (x < 32) {
        const float* src = k + (size_t)bh * S_LEN * D_DIM + (size_t)x * 8192;
        u16* dst = kw + (size_t)bh * S_LEN * D_DIM + (size_t)x * 8192;
        #pragma unroll
        for (int i = 0; i < 8; ++i) {
            int e = i * 1024 + tid * 4;
            float4 xx = *(const float4*)(src + e);
            ushort4 h;
            h.x = f2b(xx.x); h.y = f2b(xx.y); h.z = f2b(xx.z); h.w = f2b(xx.w);
            *(ushort4*)(dst + e) = h;
        }
    } else {
        __shared__ float T[128][65];
        const int t  = x - 32;            // 0..31
        const int s0 = (t >> 1) * 128;
        const int d0 = (t & 1) * 64;
        const float* vb = v + ((size_t)bh * S_LEN + s0) * D_DIM + d0;
        #pragma unroll
        for (int i = 0; i < 8; ++i) {
            int unit = i * 256 + tid;
            int ss = unit >> 4;
            int c  = (unit & 15) * 4;
            float4 xx = *(const float4*)(vb + ss * D_DIM + c);
            T[ss][c + 0] = xx.x; T[ss][c + 1] = xx.y;
            T[ss][c + 2] = xx.z; T[ss][c + 3] = xx.w;
        }
        __syncthreads();
        u16* ob = vt + (size_t)bh * D_DIM * S_LEN + (size_t)d0 * S_LEN + s0;
        #pragma unroll
        for (int i = 0; i < 8; ++i) {
            int unit = i * 256 + tid;
            int d  = unit >> 5;
            int sl = (unit & 31) * 4;
            ushort4 h;
            h.x = f2b(T[sl + 0][d]); h.y = f2b(T[sl + 1][d]);
            h.z = f2b(T[sl + 2][d]); h.w = f2b(T[sl + 3][d]);
            *(ushort4*)(ob + (size_t)d * S_LEN + sl) = h;
        }
    }
}

// r18: BM=256, 1024 threads, 1 BLOCK/CU, C18 18-tile walker.
// R12 failed on launch bounds, not the model: (1024,8) -> 64-VGPR cap ->
// VGPR=32 + 600MB scratch; experiment never ran. Pinned constraint: body
// fits at 4 waves/EU (128 cap -> 64 VGPR, R10) not 8. The cadence model
// (R10==R11: per-visit time invariant to per-wave volume & waves/CU) does
// NOT need 2 blocks/CU -- it needs FEWER VISITS. So: 256 blocks x exactly
// 18 tiles, 1 block/CU, single round, perfectly balanced. Per-CU visits
// 34 -> 18; solo-visit ~2.8-3.0us (R1) -> fa ~52-62 predicted; ~90 = null.
// phi shrinks to 7 extras/bh (29.4MB, ws total ~63MB < 98.6 proven).
__constant__ signed char C18_QT[15] = {0,1,2, 2,3, 3,4, 4,5, 5,6, 6, 6,7, 7};
__constant__ signed char C18_T0[15] = {0,0,0, 6,0, 12,0, 14,0, 12,0, 6, 24,0, 14};
__constant__ signed char C18_T1[15] = {4,8,6, 12,12, 16,14, 20,12, 24,6, 24, 28,14, 32};
__constant__ signed char C18_P [15] = {-1,-1,0, 1,0, 1,0, 1,0, 1,0, 1, 2,0, 1};
__constant__ signed char C18_OFF[9] = {0,3,5,7,9,11,12,14,15};
__constant__ signed char C18_NP[8] = {1,1,2,2,2,2,3,2};
__constant__ signed char C18_EB[8] = {0,0,0,1,2,3,4,6};

__global__ __launch_bounds__(1024, 4) void fa_bal(const float* __restrict__ q,
                                                  const u16* __restrict__ kw,
                                                  const u16* __restrict__ vtw,
                                                  float* __restrict__ out,
                                                  float* __restrict__ phi,
                                                  float* __restrict__ mlb) {
    __shared__ u16 Ks[2][BN * D_DIM];
    __shared__ u16 Vt[2][D_DIM * BN];

    const int bh = blockIdx.x & 31;
    const int s  = blockIdx.x >> 5;        // 8 slots/bh, all exactly 18 tiles
    const int tid  = threadIdx.x;
    const int w    = tid >> 6;             // 0..15
    const int lane = tid & 63;
    const int ln   = lane & 15;
    const int quad = lane >> 4;
    constexpr float qs = 0.08838834764831845f * 1.44269504088896340f;

    const u16* kb_bh = kw + (size_t)bh * S_LEN * D_DIM;
    const u16* vb_bh = vtw + (size_t)bh * D_DIM * S_LEN;

    auto stage = [&](int t, int b) {
        const int n0 = t * BN;
        const u16* kb = kb_bh + (size_t)n0 * D_DIM;
        {
            int R0 = w * 4;                // 16 waves x 4 rows = 64
            int r = R0 + (lane >> 4);
            int p = lane & 15;
            gld_lds16(kb + r * D_DIM + ((p ^ (r & 7)) << 3), &Ks[b][R0 * D_DIM]);
        }
        {
            int D0 = w * 8;                // 16 waves x 8 rows = 128
            int d = D0 + (lane >> 3);
            int p = lane & 7;
            gld_lds16(vb_bh + (size_t)d * S_LEN + n0 + ((p ^ (d & 7)) << 3),
                      &Vt[b][D0 * BN]);
        }
    };

    const int cbeg = C18_OFF[s], cend = C18_OFF[s + 1];
    int pb = 0;
    stage(C18_T0[cbeg], 0);

    for (int c = cbeg; c < cend; ++c) {
        const int qt = C18_QT[c], t0 = C18_T0[c], t1 = C18_T1[c];
        const int pp = C18_P[c];
        const int q0 = qt * 256;
        const int rowb0 = q0 + w * 16;     // this wave's 16 q-rows: rowb0 + ln

        // ---- Q fragments (scale*log2e folded) ----
        short8 qf[4];
        {
            const float* qrow = q + ((size_t)bh * S_LEN + rowb0 + ln) * D_DIM;
            #pragma unroll
            for (int kc = 0; kc < 4; ++kc) {
                const float* p = qrow + kc * 32 + quad * 8;
                float4 x0 = *(const float4*)(p);
                float4 x1 = *(const float4*)(p + 4);
                short8 f;
                f[0] = (short)f2b(x0.x * qs); f[1] = (short)f2b(x0.y * qs);
                f[2] = (short)f2b(x0.z * qs); f[3] = (short)f2b(x0.w * qs);
                f[4] = (short)f2b(x1.x * qs); f[5] = (short)f2b(x1.y * qs);
                f[6] = (short)f2b(x1.z * qs); f[7] = (short)f2b(x1.w * qs);
                qf[kc] = f;
            }
        }

        floatx4 o[8];
        #pragma unroll
        for (int db = 0; db < 8; ++db) o[db] = (floatx4){0.f, 0.f, 0.f, 0.f};
        float m_i = -1e30f;
        float l_i = 0.f;

        for (int t = t0; t < t1; ++t) {
            __syncthreads();
            {
                int nt = (t + 1 < t1) ? (t + 1) : ((c + 1 < cend) ? (int)C18_T0[c + 1] : -1);
                if (nt >= 0) stage(nt, pb ^ 1);
            }
            const u16* ks = Ks[pb];
            const u16* vs = Vt[pb];
            pb ^= 1;
            const int n0 = t * BN;
            if (n0 > rowb0 + 15) continue;   // wave-uniform: fully masked tile

            // ---- S^T = K Q^T ----
            floatx4 sc[4];
            #pragma unroll
            for (int nb = 0; nb < 4; ++nb) {
                short8 kf[4];
                #pragma unroll
                for (int kc = 0; kc < 4; ++kc) {
                    int r = nb * 16 + ln;
                    kf[kc] = *(const short8*)&ks[r * D_DIM + (((kc * 4 + quad) ^ (r & 7)) << 3)];
                }
                floatx4 a = (floatx4){0.f, 0.f, 0.f, 0.f};
                #pragma unroll
                for (int kc = 0; kc < 4; ++kc) a = mfma16(kf[kc], qf[kc], a);
                sc[nb] = a;
            }

            // ---- mask, online softmax (T13), B-frag build ----
            const int qrow = rowb0 + ln;
            if (n0 + 63 > rowb0) {
                #pragma unroll
                for (int nb = 0; nb < 4; ++nb) {
                    int kvb = n0 + nb * 16 + quad * 4;
                    #pragma unroll
                    for (int r = 0; r < 4; ++r)
                        if (kvb + r > qrow) sc[nb][r] = -1e30f;
                }
            }
            float mx;
            {
                floatx4 m01, m23;
                #pragma unroll
                for (int r = 0; r < 4; ++r) {
                    m01[r] = fmaxf(sc[0][r], sc[1][r]);
                    m23[r] = fmaxf(sc[2][r], sc[3][r]);
                }
                floatx4 mm;
                #pragma unroll
                for (int r = 0; r < 4; ++r) mm[r] = fmaxf(m01[r], m23[r]);
                mx = fmaxf(fmaxf(mm[0], mm[1]), fmaxf(mm[2], mm[3]));
            }
            mx = fmaxf(mx, __shfl_xor(mx, 16));
            mx = fmaxf(mx, __shfl_xor(mx, 32));
            if (!__all(mx <= m_i + 8.f)) {
                float mn = fmaxf(m_i, mx);
                float al = __builtin_amdgcn_exp2f(m_i - mn);
                m_i = mn;
                l_i *= al;
                #pragma unroll
                for (int db = 0; db < 8; ++db) o[db] *= al;
            }
            const float mn = m_i;
            float rsn[4];
            unsigned pk0[4], pk1[4];
            #pragma unroll
            for (int nb = 0; nb < 4; ++nb) {
                u16 h[4];
                #pragma unroll
                for (int r = 0; r < 4; ++r) {
                    float p = __builtin_amdgcn_exp2f(sc[nb][r] - mn);
                    h[r] = f2b(p);
                }
                rsn[nb] = (b2f(h[0]) + b2f(h[1])) + (b2f(h[2]) + b2f(h[3]));
                pk0[nb] = (unsigned)h[0] | ((unsigned)h[1] << 16);
                pk1[nb] = (unsigned)h[2] | ((unsigned)h[3] << 16);
            }
            float rs = (rsn[0] + rsn[1]) + (rsn[2] + rsn[3]);
            rs += __shfl_xor(rs, 16);
            rs += __shfl_xor(rs, 32);
            l_i += rs;

            short8 bfr[2];
            const int s0l = ((quad & 1) << 5) + ln;
            const int s1l = s0l + 16;
            const bool hiq = (quad >> 1) != 0;
            #pragma unroll
            for (int p = 0; p < 2; ++p) {
                unsigned l0 = __shfl((int)pk0[2 * p], s0l), h0 = __shfl((int)pk0[2 * p + 1], s0l);
                unsigned l1 = __shfl((int)pk1[2 * p], s0l), h1 = __shfl((int)pk1[2 * p + 1], s0l);
                unsigned l2 = __shfl((int)pk0[2 * p], s1l), h2 = __shfl((int)pk0[2 * p + 1], s1l);
                unsigned l3 = __shfl((int)pk1[2 * p], s1l), h3 = __shfl((int)pk1[2 * p + 1], s1l);
                union { uintx4 u; short8 s; } bc;
                bc.u = (uintx4){hiq ? h0 : l0, hiq ? h1 : l1, hiq ? h2 : l2, hiq ? h3 : l3};
                bfr[p] = bc.s;
            }

            // ---- O^T += V^T P^T ----
            #pragma unroll
            for (int db = 0; db < 8; ++db) {
                int d = db * 16 + ln;
                short8 v0 = *(const short8*)&vs[d * BN + ((quad ^ (d & 7)) << 3)];
                short8 v1 = *(const short8*)&vs[d * BN + (((4 + quad) ^ (d & 7)) << 3)];
                o[db] = mfma16(v0, bfr[0], o[db]);
                o[db] = mfma16(v1, bfr[1], o[db]);
            }
        }

        // ---- chunk epilogue ----
        if (pp < 0) {
            float inv = 1.f / l_i;
            size_t row = (size_t)bh * S_LEN + rowb0 + ln;
            float* orow = out + row * D_DIM + quad * 4;
            #pragma unroll
            for (int db = 0; db < 8; ++db) {
                float4 st = {o[db][0] * inv, o[db][1] * inv,
                             o[db][2] * inv, o[db][3] * inv};
                *(float4*)(orow + db * 16) = st;
            }
        } else {
            const int r = w * 16 + ln;                 // row within q-tile 0..255
            float* base = (pp == 0)
                ? out + ((size_t)bh * S_LEN + q0) * D_DIM
                : phi + (size_t)(bh * 7 + C18_EB[qt] + pp - 1) * (256 * D_DIM);
            float* orow = base + (size_t)r * D_DIM + quad * 4;
            #pragma unroll
            for (int db = 0; db < 8; ++db) {
                float4 st = {o[db][0], o[db][1], o[db][2], o[db][3]};
                *(float4*)(orow + db * 16) = st;
            }
            if (quad == 0) {
                float* mlq = mlb + (size_t)((bh * 8 + qt) * 3 + pp) * 512;
                mlq[r] = m_i;
                mlq[256 + r] = l_i;
            }
        }
    }
}

// ---------------- np-way flash-combine (log2 domain) ----------------
__constant__ signed char M_QT[6] = {2,3,4,5,6,7};
__constant__ signed char M_NP[6] = {2,2,2,2,3,2};
__constant__ signed char M_EB[6] = {0,1,2,3,4,6};

__global__ __launch_bounds__(512) void merge18(float* __restrict__ out,
                                               const float* __restrict__ phi,
                                               const float* __restrict__ mlb) {
    const int item = blockIdx.x;         // 6*32: split-qt x bh
    const int sq = item % 6;
    const int bh = item / 6;
    const int qt = M_QT[sq];
    const int np = M_NP[sq];
    const int eb = M_EB[sq];
    const int tid = threadIdx.x;
    const int r  = tid >> 1;             // row 0..255
    const int hf = (tid & 1) * 64;       // d half
    const size_t mlB = (size_t)((bh * 8 + qt) * 3) * 512;
    float mP[3], lP[3];
    float ms = -1e30f;
    #pragma unroll
    for (int p = 0; p < 3; ++p) {
        if (p < np) {
            mP[p] = mlb[mlB + p * 512 + r];
            lP[p] = mlb[mlB + p * 512 + 256 + r];
            ms = fmaxf(ms, mP[p]);
        }
    }
    float a[3], ls = 0.f;
    #pragma unroll
    for (int p = 0; p < 3; ++p) {
        if (p < np) {
            a[p] = __builtin_amdgcn_exp2f(mP[p] - ms);
            ls += lP[p] * a[p];
        }
    }
    float inv = 1.f / ls;
    float* orow = out + ((size_t)bh * S_LEN + qt * 256 + r) * D_DIM + hf;
    const float* e1 = phi + ((size_t)(bh * 7 + eb + 0) * 256 + r) * D_DIM + hf;
    const float* e2 = phi + ((size_t)(bh * 7 + eb + 1) * 256 + r) * D_DIM + hf;
    #pragma unroll
    for (int i = 0; i < 16; ++i) {
        float4 acc = *(const float4*)(orow + i * 4);
        acc.x *= a[0]; acc.y *= a[0]; acc.z *= a[0]; acc.w *= a[0];
        float4 e = *(const float4*)(e1 + i * 4);
        acc.x += e.x * a[1]; acc.y += e.y * a[1]; acc.z += e.z * a[1]; acc.w += e.w * a[1];
        if (np > 2) {
            float4 f = *(const float4*)(e2 + i * 4);
            acc.x += f.x * a[2]; acc.y += f.y * a[2]; acc.z += f.z * a[2]; acc.w += f.w * a[2];
        }
        float4 st = {acc.x * inv, acc.y * inv, acc.z * inv, acc.w * inv};
        *(float4*)(orow + i * 4) = st;
    }
}

extern "C" void kernel_launch(void* const* d_in, const int* in_sizes, int n_in,
                              void* d_out, int out_size, void* d_ws, size_t ws_size,
                              hipStream_t stream) {
    const float* q = (const float*)d_in[0];
    const float* k = (const float*)d_in[1];
    const float* v = (const float*)d_in[2];
    float* out = (float*)d_out;
    const int nbh = in_sizes[0] / (S_LEN * D_DIM);    // 32
    const size_t kelems = (size_t)nbh * S_LEN * D_DIM;

    u16* kw = (u16*)d_ws;                              // 16.78 MB
    u16* vt = kw + kelems;                             // 16.78 MB
    float* phi = (float*)(vt + kelems);                // 7*nbh*256*128 f32 = 29.4 MB
    float* mlb = phi + (size_t)7 * nbh * 256 * D_DIM;  // nbh*8*3*512 f32 = 1.6 MB
    // total ~64.7 MB < 98.6 MB proven available (R8).

    prep_kv<<<dim3(64, nbh), 256, 0, stream>>>(k, v, kw, vt);
    fa_bal<<<dim3(8 * nbh), 1024, 0, stream>>>(q, kw, vt, out, phi, mlb);
    merge18<<<dim3(6 * nbh), 512, 0, stream>>>(out, phi, mlb);
}

// Round 14
// 197.870 us; speedup vs baseline: 2.4257x; 1.2561x over previous
//
#include <hip/hip_runtime.h>

#define S_LEN 2048
#define D_DIM 128
#define BM 128
#define BN 64
#define NQT (S_LEN / BM)   // 16

typedef __attribute__((ext_vector_type(8))) short short8;
typedef __attribute__((ext_vector_type(4))) float floatx4;
typedef __attribute__((ext_vector_type(4))) unsigned uintx4;
typedef unsigned short u16;

__device__ __forceinline__ u16 f2b(float f) {
    union { float f; unsigned u; } x; x.f = f;
    unsigned r = x.u + 0x7FFFu + ((x.u >> 16) & 1u);  // RNE
    return (u16)(r >> 16);
}
__device__ __forceinline__ float b2f(u16 h) {
    union { unsigned u; float f; } x; x.u = ((unsigned)h) << 16;
    return x.f;
}
__device__ __forceinline__ void gld_lds16(const void* g, void* l) {
    __builtin_amdgcn_global_load_lds(
        (const __attribute__((address_space(1))) unsigned int*)g,
        (__attribute__((address_space(3))) unsigned int*)l, 16, 0, 0);
}
__device__ __forceinline__ floatx4 mfma16(short8 a, short8 b, floatx4 c) {
    return __builtin_amdgcn_mfma_f32_16x16x32_bf16(a, b, c, 0, 0, 0);
}

// ---------------- fused pre-pass: K fp32->bf16 (x<32) | V transpose (x>=32) ----
// REVERTED to the R4/64x64 version (the 128x65 retile coincided with a ~20us
// residual regression: 33KB LDS -> ~4 blocks/CU vs 9; R4's residual 110 vs
// 150+ on every round carrying the retile). Proven in the best total (199.15).
__global__ __launch_bounds__(256) void prep_kv(const float* __restrict__ k,
                                               const float* __restrict__ v,
                                               u16* __restrict__ kw,
                                               u16* __restrict__ vt) {
    const int x   = blockIdx.x;
    const int bh  = blockIdx.y;
    const int tid = threadIdx.x;
    if (x < 32) {
        const float* src = k + (size_t)bh * S_LEN * D_DIM + (size_t)x * 8192;
        u16* dst = kw + (size_t)bh * S_LEN * D_DIM + (size_t)x * 8192;
        #pragma unroll
        for (int i = 0; i < 8; ++i) {
            int e = i * 1024 + tid * 4;
            float4 xx = *(const float4*)(src + e);
            ushort4 h;
            h.x = f2b(xx.x); h.y = f2b(xx.y); h.z = f2b(xx.z); h.w = f2b(xx.w);
            *(ushort4*)(dst + e) = h;
        }
    } else {
        __shared__ float T[64][65];
        const int t  = x - 32;           // 0..63
        const int s0 = (t >> 1) * 64;
        const int d0 = (t & 1) * 64;
        const float* vb = v + ((size_t)bh * S_LEN + s0) * D_DIM + d0;
        #pragma unroll
        for (int i = 0; i < 4; ++i) {
            int unit = i * 256 + tid;
            int s = unit >> 4;
            int c = (unit & 15) * 4;
            float4 xx = *(const float4*)(vb + s * D_DIM + c);
            T[s][c + 0] = xx.x; T[s][c + 1] = xx.y;
            T[s][c + 2] = xx.z; T[s][c + 3] = xx.w;
        }
        __syncthreads();
        u16* ob = vt + (size_t)bh * D_DIM * S_LEN + (size_t)d0 * S_LEN + s0;
        #pragma unroll
        for (int i = 0; i < 4; ++i) {
            int unit = i * 256 + tid;
            int d  = unit >> 4;
            int sl = (unit & 15) * 4;
            ushort4 h;
            h.x = f2b(T[sl + 0][d]); h.y = f2b(T[sl + 1][d]);
            h.z = f2b(T[sl + 2][d]); h.w = f2b(T[sl + 3][d]);
            *(ushort4*)(ob + (size_t)d * S_LEN + sl) = h;
        }
    }
}

// ---------------- monolithic flash kernel, transposed-S, dbuf staging ----------
// r19 = R4 (best total, 199.15us; fa 88.9) + DEFER-L:
// R13 closed the scheduling axis: per-(128q x 64kv)-unit cost is ~2.6us
// invariant across 6 schedules/shapes/residencies -> cost lives in the
// per-unit dependency chains, not barriers. Cut the chain: the per-visit
// rs shfl_xor(16)+shfl_xor(32) pair (2 serial lgkm round-trips) is removable
// because l is only consumed in the epilogue and the rescale factor al is
// row-uniform -> a PER-LANE partial l stays exact under T13 rescale; reduce
// across quads ONCE per block (2 shfls total vs 2 x ~17 visits).
__global__ __launch_bounds__(512, 4) void fa_main(const float* __restrict__ q,
                                                  const u16* __restrict__ kw,
                                                  const u16* __restrict__ vtw,
                                                  float* __restrict__ out) {
    __shared__ u16 Ks[2][BN * D_DIM];   // XOR-swizzled granules
    __shared__ u16 Vt[2][D_DIM * BN];   // XOR-swizzled granules

    // complementary-pair balanced mapping (proven): per-CU work uniform
    const int n  = blockIdx.x;
    const int hi = n >> 8;
    const int ii = n & 255;
    const int qt = hi ? (ii & 15) : 15 - (ii & 15);
    const int bh = hi * 16 + (ii >> 4);

    const int q0   = qt * BM;
    const int tid  = threadIdx.x;
    const int w    = tid >> 6;
    const int lane = tid & 63;
    const int ln   = lane & 15;
    const int quad = lane >> 4;
    constexpr float qs = 0.08838834764831845f * 1.44269504088896340f;
    const int rowb0 = q0 + w * 16;   // this wave's 16 q-rows: rowb0 + ln

    // ---- Q fragments (B-operand; layout identical to A), scale*log2e folded ----
    short8 qf[4];
    {
        const float* qrow = q + ((size_t)bh * S_LEN + rowb0 + ln) * D_DIM;
        #pragma unroll
        for (int kc = 0; kc < 4; ++kc) {
            const float* p = qrow + kc * 32 + quad * 8;
            float4 x0 = *(const float4*)(p);
            float4 x1 = *(const float4*)(p + 4);
            short8 f;
            f[0] = (short)f2b(x0.x * qs); f[1] = (short)f2b(x0.y * qs);
            f[2] = (short)f2b(x0.z * qs); f[3] = (short)f2b(x0.w * qs);
            f[4] = (short)f2b(x1.x * qs); f[5] = (short)f2b(x1.y * qs);
            f[6] = (short)f2b(x1.z * qs); f[7] = (short)f2b(x1.w * qs);
            qf[kc] = f;
        }
    }

    floatx4 o[8];   // O^T accs: col=ln=qrow, row=quad*4+reg = d within db-block
    #pragma unroll
    for (int db = 0; db < 8; ++db) o[db] = (floatx4){0.f, 0.f, 0.f, 0.f};
    float m_i = -1e30f;
    float l_p = 0.f;   // PER-LANE partial of l (this lane's 16 kv slots/visit)

    const u16* kb_bh = kw + (size_t)bh * S_LEN * D_DIM;
    const u16* vb_bh = vtw + (size_t)bh * D_DIM * S_LEN;
    const int NT = 2 * qt + 2;

    auto stage = [&](int t, int b) {
        const int n0 = t * BN;
        const u16* kb = kb_bh + (size_t)n0 * D_DIM;
        #pragma unroll
        for (int i = 0; i < 2; ++i) {
            int R0 = w * 8 + i * 4;            // 8 waves x 2 calls x 4 rows = 64
            int r = R0 + (lane >> 4);
            int p = lane & 15;
            gld_lds16(kb + r * D_DIM + ((p ^ (r & 7)) << 3), &Ks[b][R0 * D_DIM]);
        }
        #pragma unroll
        for (int i = 0; i < 2; ++i) {
            int D0 = (w * 2 + i) * 8;          // 8 waves x 2 calls x 8 rows = 128
            int d = D0 + (lane >> 3);
            int p = lane & 7;
            gld_lds16(vb_bh + (size_t)d * S_LEN + n0 + ((p ^ (d & 7)) << 3),
                      &Vt[b][D0 * BN]);
        }
    };

    stage(0, 0);

    for (int t = 0; t < NT; ++t) {
        __syncthreads();                       // buf[t&1] staged (drain hidden)
        if (t + 1 < NT) stage(t + 1, (t + 1) & 1);   // prefetch next tile
        const u16* ks = Ks[t & 1];
        const u16* vs = Vt[t & 1];
        const int n0 = t * BN;
        if (n0 > rowb0 + 15) continue;         // wave-uniform: fully masked tile

        // ---- S^T = K Q^T : col=ln=qrow, row=quad*4+reg = kv within nb-block ----
        floatx4 sc[4];
        #pragma unroll
        for (int nb = 0; nb < 4; ++nb) {
            short8 kf[4];
            #pragma unroll
            for (int kc = 0; kc < 4; ++kc) {
                int r = nb * 16 + ln;
                kf[kc] = *(const short8*)&ks[r * D_DIM + (((kc * 4 + quad) ^ (r & 7)) << 3)];
            }
            floatx4 a = (floatx4){0.f, 0.f, 0.f, 0.f};
            #pragma unroll
            for (int kc = 0; kc < 4; ++kc) a = mfma16(kf[kc], qf[kc], a);
            sc[nb] = a;
        }

        // ---- mask, online softmax (deferred-rescale + deferred-l) ----
        const int qrow = rowb0 + ln;
        if (n0 + 63 > rowb0) {   // diagonal region: elementwise causal mask
            #pragma unroll
            for (int nb = 0; nb < 4; ++nb) {
                int kvb = n0 + nb * 16 + quad * 4;
                #pragma unroll
                for (int r = 0; r < 4; ++r)
                    if (kvb + r > qrow) sc[nb][r] = -1e30f;
            }
        }
        // tree max over 16 in-lane (depth 4, max3-fusable) + 2 shfls
        float mx;
        {
            floatx4 m01, m23;
            #pragma unroll
            for (int r = 0; r < 4; ++r) {
                m01[r] = fmaxf(sc[0][r], sc[1][r]);
                m23[r] = fmaxf(sc[2][r], sc[3][r]);
            }
            floatx4 mm;
            #pragma unroll
            for (int r = 0; r < 4; ++r) mm[r] = fmaxf(m01[r], m23[r]);
            mx = fmaxf(fmaxf(mm[0], mm[1]), fmaxf(mm[2], mm[3]));
        }
        mx = fmaxf(mx, __shfl_xor(mx, 16));
        mx = fmaxf(mx, __shfl_xor(mx, 32));
        // T13: defer rescale while max growth <= 8 (P bounded by e^8).
        // al is row-uniform -> per-lane partial l scales correctly.
        if (!__all(mx <= m_i + 8.f)) {
            float mn = fmaxf(m_i, mx);
            float al = __builtin_amdgcn_exp2f(m_i - mn);
            m_i = mn;
            l_p *= al;
            #pragma unroll
            for (int db = 0; db < 8; ++db) o[db] *= al;
        }
        const float mn = m_i;
        float rsn[4];
        unsigned pk0[4], pk1[4];
        #pragma unroll
        for (int nb = 0; nb < 4; ++nb) {
            u16 h[4];
            #pragma unroll
            for (int r = 0; r < 4; ++r) {
                float p = __builtin_amdgcn_exp2f(sc[nb][r] - mn);
                h[r] = f2b(p);
            }
            // rounded values: num/denom consistent; pairwise tree
            rsn[nb] = (b2f(h[0]) + b2f(h[1])) + (b2f(h[2]) + b2f(h[3]));
            pk0[nb] = (unsigned)h[0] | ((unsigned)h[1] << 16);
            pk1[nb] = (unsigned)h[2] | ((unsigned)h[3] << 16);
        }
        // DEFER-L: accumulate lane-local; cross-quad reduce once in epilogue
        l_p += (rsn[0] + rsn[1]) + (rsn[2] + rsn[3]);

        // B-frag (K=32) for kv-block p: lane(q,ln) needs kv=32p+8q+j.
        // src: nb=2p+(q>>1), src quads {2(q&1), 2(q&1)+1}.
        short8 bfr[2];
        const int s0l = ((quad & 1) << 5) + ln;   // src lane: quad 2*(q&1), same ln
        const int s1l = s0l + 16;                 // src lane: quad 2*(q&1)+1
        const bool hiq = (quad >> 1) != 0;
        #pragma unroll
        for (int p = 0; p < 2; ++p) {
            unsigned l0 = __shfl((int)pk0[2 * p], s0l), h0 = __shfl((int)pk0[2 * p + 1], s0l);
            unsigned l1 = __shfl((int)pk1[2 * p], s0l), h1 = __shfl((int)pk1[2 * p + 1], s0l);
            unsigned l2 = __shfl((int)pk0[2 * p], s1l), h2 = __shfl((int)pk0[2 * p + 1], s1l);
            unsigned l3 = __shfl((int)pk1[2 * p], s1l), h3 = __shfl((int)pk1[2 * p + 1], s1l);
            union { uintx4 u; short8 s; } bc;
            bc.u = (uintx4){hiq ? h0 : l0, hiq ? h1 : l1, hiq ? h2 : l2, hiq ? h3 : l3};
            bfr[p] = bc.s;
        }

        // ---- O^T += V^T P^T : A = Vt rows (b128), inline reads ----
        #pragma unroll
        for (int db = 0; db < 8; ++db) {
            int d = db * 16 + ln;
            short8 v0 = *(const short8*)&vs[d * BN + ((quad ^ (d & 7)) << 3)];
            short8 v1 = *(const short8*)&vs[d * BN + (((4 + quad) ^ (d & 7)) << 3)];
            o[db] = mfma16(v0, bfr[0], o[db]);
            o[db] = mfma16(v1, bfr[1], o[db]);
        }
    }

    // ---- epilogue: reduce l across quads ONCE, then O = (O^T)^T / l ----
    {
        float lt = l_p;
        lt += __shfl_xor(lt, 16);
        lt += __shfl_xor(lt, 32);
        float inv = 1.f / lt;
        size_t row = (size_t)bh * S_LEN + rowb0 + ln;
        float* orow = out + row * D_DIM + quad * 4;
        #pragma unroll
        for (int db = 0; db < 8; ++db) {
            float4 st = {o[db][0] * inv, o[db][1] * inv,
                         o[db][2] * inv, o[db][3] * inv};
            *(float4*)(orow + db * 16) = st;
        }
    }
}

extern "C" void kernel_launch(void* const* d_in, const int* in_sizes, int n_in,
                              void* d_out, int out_size, void* d_ws, size_t ws_size,
                              hipStream_t stream) {
    const float* q = (const float*)d_in[0];
    const float* k = (const float*)d_in[1];
    const float* v = (const float*)d_in[2];
    float* out = (float*)d_out;
    const int bh = in_sizes[0] / (S_LEN * D_DIM);     // 32
    const size_t kelems = (size_t)bh * S_LEN * D_DIM; // 8.39M

    u16* kw = (u16*)d_ws;
    u16* vt = kw + kelems;
    prep_kv<<<dim3(96, bh), 256, 0, stream>>>(k, v, kw, vt);
    fa_main<<<dim3(NQT * bh), 512, 0, stream>>>(q, kw, vt, out);
}